// Round 1
// 1596.620 us; speedup vs baseline: 1.0246x; 1.0246x over previous
//
#include <hip/hip_runtime.h>
#include <hip/hip_bf16.h>

typedef __hip_bfloat16 bf16;
typedef __attribute__((ext_vector_type(8))) short short8;
typedef __attribute__((ext_vector_type(4))) float float4v;

#define BK 32

__device__ __forceinline__ void gload16(const bf16* g, bf16* s) {
    __builtin_amdgcn_global_load_lds(
        (const __attribute__((address_space(1))) void*)g,
        (__attribute__((address_space(3))) void*)s, 16, 0, 0);
}

// raw barrier (no vmcnt drain) + compiler memory fence so loads/stores can't cross
#define BAR() do { asm volatile("" ::: "memory"); __builtin_amdgcn_s_barrier(); asm volatile("" ::: "memory"); } while (0)

// ---------------- small utility kernels ----------------

__global__ void k_convert_x(const float* __restrict__ in, bf16* __restrict__ out,
                            int n, int* __restrict__ cnt) {
    if (blockIdx.x == 0 && threadIdx.x < 16) cnt[threadIdx.x] = 0;
    int i = (blockIdx.x * blockDim.x + threadIdx.x) * 4;
    if (i + 3 < n) {
        float4 v = *(const float4*)(in + i);
        out[i + 0] = __float2bfloat16(v.x);
        out[i + 1] = __float2bfloat16(v.y);
        out[i + 2] = __float2bfloat16(v.z);
        out[i + 3] = __float2bfloat16(v.w);
    }
}

// in: [R,S] fp32 -> out: [S,R] bf16 (batched over z). 64x64 tile, 256 threads.
// fuse=1 (FC weights, S=6144): output row is remapped to the 16-col gate/val
// interleave: s -> (idx>>4)<<5 | half<<4 | idx&15, so one 256-row B^T tile
// covers 128 output cols as (gate,val) 16-row pairs -> SwiGLU fuses in-register.
__global__ __launch_bounds__(256) void k_transpose64(
    const float* __restrict__ in, bf16* __restrict__ out, int R, int S, int fuse) {
    __shared__ float tile[64][65];
    size_t mat = (size_t)blockIdx.z * R * S;
    int s0 = blockIdx.x * 64, r0 = blockIdx.y * 64;
    int tid = threadIdx.x;
    int rr = tid >> 4, sc = (tid & 15) * 4;
    #pragma unroll
    for (int i = 0; i < 4; ++i) {
        float4 v = *(const float4*)(in + mat + (size_t)(r0 + rr + i * 16) * S + s0 + sc);
        tile[rr + i * 16][sc + 0] = v.x;
        tile[rr + i * 16][sc + 1] = v.y;
        tile[rr + i * 16][sc + 2] = v.z;
        tile[rr + i * 16][sc + 3] = v.w;
    }
    __syncthreads();
    int ss = tid >> 3, rc = (tid & 7) * 8;
    #pragma unroll
    for (int i = 0; i < 2; ++i) {
        int sl = ss + i * 32;
        int sg = s0 + sl;
        int so = sg;
        if (fuse) {
            int half = (sg >= 3072) ? 1 : 0;
            int idx = sg - half * 3072;
            so = ((idx >> 4) << 5) | (half << 4) | (idx & 15);
        }
        bf16 tmp[8];
        #pragma unroll
        for (int j = 0; j < 8; ++j) tmp[j] = __float2bfloat16(tile[rc + j][sl]);
        *(uint4*)(out + mat + (size_t)so * R + r0 + rc) = *(uint4*)tmp;
    }
}

// gate: fp32 logits, sigmoid, top-4, normalize, build expert lists + token-major slots
__global__ void k_gate(const float* __restrict__ x, const float* __restrict__ wg,
                       const float* __restrict__ bias, int* __restrict__ cnt,
                       int* __restrict__ tok, float* __restrict__ wl,
                       int* __restrict__ slotk) {
    __shared__ float gates[16][17];
    int t = threadIdx.x;
    int tl = t >> 4;
    int e = t & 15;
    int token = blockIdx.x * 16 + tl;
    const float* xr = x + (size_t)token * 768;
    float acc = 0.f;
    #pragma unroll 4
    for (int c = 0; c < 768; ++c) acc += xr[c] * wg[c * 16 + e];
    acc += bias[e];
    gates[tl][e] = 1.f / (1.f + expf(-acc));
    __syncthreads();
    if (t < 16) {
        int token2 = blockIdx.x * 16 + t;
        float g[16];
        #pragma unroll
        for (int j = 0; j < 16; ++j) g[j] = gates[t][j];
        int idx[4]; float w[4]; float sum = 0.f;
        #pragma unroll
        for (int k = 0; k < 4; ++k) {
            float best = -1e30f; int bi = 0;
            #pragma unroll
            for (int j = 0; j < 16; ++j)
                if (g[j] > best) { best = g[j]; bi = j; }
            idx[k] = bi; w[k] = best; sum += best; g[bi] = -1e30f;
        }
        float inv = 1.f / sum;
        for (int k = 0; k < 4; ++k) {
            int slot = atomicAdd(&cnt[idx[k]], 1);
            tok[(idx[k] << 13) + slot] = token2;
            wl[(idx[k] << 13) + slot] = w[k] * inv;
            slotk[token2 * 4 + k] = (idx[k] << 13) | slot;
        }
    }
}

__global__ void k_offsets(const int* __restrict__ cnt, int* __restrict__ offs) {
    if (threadIdx.x == 0) {
        int s = 0;
        for (int e = 0; e < 16; ++e) { offs[e] = s; s += cnt[e]; }
    }
}

// combine: out[t] += sum_k routed[offs[e_k] + slot_k]   (weights applied in proj)
__global__ __launch_bounds__(192) void k_combine(
    const float* __restrict__ routed, const int* __restrict__ slotk,
    const int* __restrict__ offs, float* __restrict__ out) {
    int t = blockIdx.x;
    int c4 = threadIdx.x * 4;
    float* op = out + (size_t)t * 768 + c4;
    float4 acc = *(float4*)op;
    #pragma unroll
    for (int k = 0; k < 4; ++k) {
        int sk = slotk[t * 4 + k];
        int e = sk >> 13, sl = sk & 8191;
        const float* row = routed + (size_t)(offs[e] + sl) * 768 + c4;
        float4 v = *(const float4*)row;
        acc.x += v.x; acc.y += v.y; acc.z += v.z; acc.w += v.w;
    }
    *(float4*)op = acc;
}

// ---------------- FC GEMM: 256x256xBK64, phase-pipelined, fused SwiGLU ----------------
// 8 waves (2M x 4N), per-wave output 128x64 (fused-N). LDS 128 KiB:
// 2 buffers x [A 256x64 | B 256x64] bf16. XOR-swizzle granule^=(row&7) applied
// on the READ side + inverse-swizzled GLOBAL source (LDS dest stays linear for
// global_load_lds). Per K-tile: 4 phases x 16 MFMA; stage A(t+1) in P0 and
// B(t+1) in P1; secure with vmcnt(4) end-of-P1 (A) and vmcnt(0) end-of-P3 (B)
// -> every load has >=2 phases of slack; no drain-at-issue anywhere.
template<int GATHER>
__device__ __forceinline__ void fc8_body(
    const bf16* __restrict__ A, const bf16* __restrict__ BT,
    bf16* __restrict__ act, const int* __restrict__ cnt,
    const int* __restrict__ offs, const int* __restrict__ tok)
{
    const int Kd = 768, H = 3072;
    int e = blockIdx.z;
    int m0 = blockIdx.y * 256;
    int n0 = blockIdx.x * 256;          // fused-interleaved B^T row base (-> 128 out cols)
    int M; size_t actbase = 0; const int* tl = nullptr;
    if (GATHER) {
        M = cnt[e];
        if (m0 >= M) return;
        tl = tok + (e << 13);
        actbase = (size_t)offs[e] * H;
        BT += (size_t)e * 6144 * Kd;
    } else {
        M = 8192;
    }

    __shared__ bf16 lds[65536];         // 128 KiB

    int tid = threadIdx.x;
    int lane = tid & 63;
    int w = tid >> 6;
    int wm = w & 1, wn = w >> 1;
    int quad = lane >> 4, l16 = lane & 15;

    // staging: per half-tile (128 rows x 64 cols) thread covers linear slots
    // tid and tid+512; slot s -> row s>>3, granule-position s&7 which holds
    // logical granule (s&7)^(row&7)  (inverse swizzle folded into global col)
    int srow = tid >> 3;                // 0..63 (and +64 for second slot)
    int g0 = (tid & 7) ^ (srow & 7);    // same for row srow and srow+64

    const bf16* gA[2][2]; const bf16* gB[2][2];
    #pragma unroll
    for (int h = 0; h < 2; ++h) {
        int ra = m0 + h * 128 + srow;
        int rb = n0 + h * 128 + srow;
        int a0 = GATHER ? tl[min(ra, M - 1)] : ra;
        int a1 = GATHER ? tl[min(ra + 64, M - 1)] : (ra + 64);
        gA[h][0] = A + (size_t)a0 * Kd + g0 * 8;
        gA[h][1] = A + (size_t)a1 * Kd + g0 * 8;
        gB[h][0] = BT + (size_t)rb * Kd + g0 * 8;
        gB[h][1] = BT + (size_t)(rb + 64) * Kd + g0 * 8;
    }

    auto stageA = [&](int buf, int kt) {
        bf16* d = lds + buf * 32768;
        gload16(gA[0][0] + kt * 64, d + tid * 8);
        gload16(gA[0][1] + kt * 64, d + (tid + 512) * 8);
        gload16(gA[1][0] + kt * 64, d + 8192 + tid * 8);
        gload16(gA[1][1] + kt * 64, d + 8192 + (tid + 512) * 8);
    };
    auto stageB = [&](int buf, int kt) {
        bf16* d = lds + buf * 32768 + 16384;
        gload16(gB[0][0] + kt * 64, d + tid * 8);
        gload16(gB[0][1] + kt * 64, d + (tid + 512) * 8);
        gload16(gB[1][0] + kt * 64, d + 8192 + tid * 8);
        gload16(gB[1][1] + kt * 64, d + 8192 + (tid + 512) * 8);
    };

    // read addressing (element offsets), 16B-aligned, conflict-free banks
    int swz0 = ((quad    ) ^ (l16 & 7)) * 8;    // ks=0
    int swz1 = ((quad | 4) ^ (l16 & 7)) * 8;    // ks=1
    int aBase = wm * 8192 + l16 * 64;
    int bBase = 16384 + wn * 4096 + l16 * 64;

    float4v acc[8][4] = {};

    stageA(0, 0);
    stageB(0, 0);
    asm volatile("s_waitcnt vmcnt(0)" ::: "memory");   // prologue only
    BAR();

    for (int t = 0; t < 12; ++t) {
        const bf16* cb = lds + (t & 1) * 32768;
        int nb = (t & 1) ^ 1;
        bool pf = (t < 11);
        short8 ar[4], br[4];

        // ---- P0: ks=0, rows wm*128+[0,64) ; stage A(t+1) ----
        #pragma unroll
        for (int nf = 0; nf < 4; ++nf)
            br[nf] = *(const short8*)(cb + bBase + nf * 1024 + swz0);
        #pragma unroll
        for (int mf = 0; mf < 4; ++mf)
            ar[mf] = *(const short8*)(cb + aBase + mf * 1024 + swz0);
        if (pf) stageA(nb, t + 1);
        __builtin_amdgcn_s_setprio(1);
        #pragma unroll
        for (int mf = 0; mf < 4; ++mf)
            #pragma unroll
            for (int nf = 0; nf < 4; ++nf)
                acc[mf][nf] = __builtin_amdgcn_mfma_f32_16x16x32_bf16(ar[mf], br[nf], acc[mf][nf], 0, 0, 0);
        __builtin_amdgcn_s_setprio(0);
        BAR();

        // ---- P1: ks=0, rows wm*128+[64,128) ; stage B(t+1); secure A(t+1) ----
        #pragma unroll
        for (int mf = 0; mf < 4; ++mf)
            ar[mf] = *(const short8*)(cb + aBase + (mf + 4) * 1024 + swz0);
        if (pf) stageB(nb, t + 1);
        __builtin_amdgcn_s_setprio(1);
        #pragma unroll
        for (int mf = 0; mf < 4; ++mf)
            #pragma unroll
            for (int nf = 0; nf < 4; ++nf)
                acc[mf + 4][nf] = __builtin_amdgcn_mfma_f32_16x16x32_bf16(ar[mf], br[nf], acc[mf + 4][nf], 0, 0, 0);
        __builtin_amdgcn_s_setprio(0);
        asm volatile("s_waitcnt vmcnt(4)" ::: "memory");   // A(t+1) landed; B(t+1) in flight
        BAR();

        // ---- P2: ks=1, rows wm*128+[0,64) ----
        #pragma unroll
        for (int nf = 0; nf < 4; ++nf)
            br[nf] = *(const short8*)(cb + bBase + nf * 1024 + swz1);
        #pragma unroll
        for (int mf = 0; mf < 4; ++mf)
            ar[mf] = *(const short8*)(cb + aBase + mf * 1024 + swz1);
        __builtin_amdgcn_s_setprio(1);
        #pragma unroll
        for (int mf = 0; mf < 4; ++mf)
            #pragma unroll
            for (int nf = 0; nf < 4; ++nf)
                acc[mf][nf] = __builtin_amdgcn_mfma_f32_16x16x32_bf16(ar[mf], br[nf], acc[mf][nf], 0, 0, 0);
        __builtin_amdgcn_s_setprio(0);
        BAR();

        // ---- P3: ks=1, rows wm*128+[64,128) ; secure B(t+1) ----
        #pragma unroll
        for (int mf = 0; mf < 4; ++mf)
            ar[mf] = *(const short8*)(cb + aBase + (mf + 4) * 1024 + swz1);
        __builtin_amdgcn_s_setprio(1);
        #pragma unroll
        for (int mf = 0; mf < 4; ++mf)
            #pragma unroll
            for (int nf = 0; nf < 4; ++nf)
                acc[mf + 4][nf] = __builtin_amdgcn_mfma_f32_16x16x32_bf16(ar[mf], br[nf], acc[mf + 4][nf], 0, 0, 0);
        __builtin_amdgcn_s_setprio(0);
        asm volatile("s_waitcnt vmcnt(0)" ::: "memory");   // only B(t+1) outstanding (2 phases old)
        BAR();
    }

    // epilogue: fused-N decode -> (gate,val) pairs share the same output column
    int orow = m0 + wm * 128;
    int ocol = (n0 + wn * 64) >> 1;
    #pragma unroll
    for (int mf = 0; mf < 8; ++mf)
        #pragma unroll
        for (int j = 0; j < 2; ++j)
            #pragma unroll
            for (int r = 0; r < 4; ++r) {
                int mrow = orow + mf * 16 + quad * 4 + r;
                if (GATHER && mrow >= M) continue;
                int col = ocol + j * 16 + l16;
                float g = acc[mf][2 * j][r];
                float v = acc[mf][2 * j + 1][r];
                float sg = g / (1.f + __expf(-g));
                act[actbase + (size_t)mrow * H + col] = __float2bfloat16(sg * v);
            }
}

__global__ __launch_bounds__(512) void k_fc_shared(
    const bf16* __restrict__ A, const bf16* __restrict__ BT, bf16* __restrict__ act,
    const int* __restrict__ cnt, const int* __restrict__ offs, const int* __restrict__ tok) {
    fc8_body<0>(A, BT, act, cnt, offs, tok);
}
__global__ __launch_bounds__(512) void k_fc_routed(
    const bf16* __restrict__ A, const bf16* __restrict__ BT, bf16* __restrict__ act,
    const int* __restrict__ cnt, const int* __restrict__ offs, const int* __restrict__ tok) {
    fc8_body<1>(A, BT, act, cnt, offs, tok);
}

// ---------------- Proj GEMM (unchanged this round) ----------------
template<int ROUTED>
__device__ __forceinline__ void proj_body(
    const bf16* __restrict__ Aact, const bf16* __restrict__ PT,
    float* __restrict__ out, const int* __restrict__ cnt,
    const int* __restrict__ offs, const float* __restrict__ wl) {
    const int Kd = 3072;
    int e = blockIdx.z;
    int m0 = blockIdx.y * 256;
    int n0 = blockIdx.x * 128;
    int M;
    size_t abase = 0;
    int roffs = 0;
    if (ROUTED) {
        M = cnt[e];
        if (m0 >= M) return;
        roffs = offs[e];
        abase = (size_t)roffs * Kd;
        PT += (size_t)e * 768 * Kd;
    } else {
        M = 8192;
    }

    __shared__ bf16 sA[256 * BK];
    __shared__ bf16 sB[128 * BK];

    int tid = threadIdx.x, lane = tid & 63, w = tid >> 6;
    int wm = w & 3, wn = w >> 2;

    int srA0 = tid >> 2;
    int srA1 = (tid + 512) >> 2;
    int k2A0 = (tid & 3) ^ ((srA0 >> 1) & 3);
    int k2A1 = (tid & 3) ^ ((srA1 >> 1) & 3);
    int srB = tid >> 2;
    int k2B = (tid & 3) ^ ((srB >> 1) & 3);

    int ra0 = min(m0 + srA0, M - 1);
    int ra1 = min(m0 + srA1, M - 1);
    const bf16* gA0 = Aact + abase + (size_t)ra0 * Kd + k2A0 * 8;
    const bf16* gA1 = Aact + abase + (size_t)ra1 * Kd + k2A1 * 8;
    const bf16* gB  = PT + (size_t)(n0 + srB) * Kd + k2B * 8;
    bf16* sA0p = sA + tid * 8;
    bf16* sA1p = sA + (tid + 512) * 8;
    bf16* sBp  = sB + tid * 8;

    float4v acc[4][4] = {};
    int quad = lane >> 4, l16 = lane & 15;
    int q2 = quad ^ ((l16 >> 1) & 3);

    for (int kk = 0; kk < Kd; kk += BK) {
        __syncthreads();
        gload16(gA0 + kk, sA0p);
        gload16(gA1 + kk, sA1p);
        gload16(gB + kk, sBp);
        __syncthreads();
        short8 af[4], bb[4];
        #pragma unroll
        for (int i = 0; i < 4; ++i) {
            int rowa = wm * 64 + i * 16 + l16;
            int rowb = wn * 64 + i * 16 + l16;
            af[i] = *(const short8*)(sA + rowa * BK + q2 * 8);
            bb[i] = *(const short8*)(sB + rowb * BK + q2 * 8);
        }
        #pragma unroll
        for (int mf = 0; mf < 4; ++mf)
            #pragma unroll
            for (int nf = 0; nf < 4; ++nf)
                acc[mf][nf] = __builtin_amdgcn_mfma_f32_16x16x32_bf16(af[mf], bb[nf], acc[mf][nf], 0, 0, 0);
    }

    #pragma unroll
    for (int mf = 0; mf < 4; ++mf) {
        #pragma unroll
        for (int r = 0; r < 4; ++r) {
            int mr = m0 + wm * 64 + mf * 16 + quad * 4 + r;
            if (ROUTED) {
                if (mr < M) {
                    float wgt = wl[(e << 13) + mr];
                    float* orow = out + (size_t)(roffs + mr) * 768;
                    #pragma unroll
                    for (int nf = 0; nf < 4; ++nf) {
                        int col = n0 + wn * 64 + nf * 16 + l16;
                        orow[col] = wgt * acc[mf][nf][r];
                    }
                }
            } else {
                #pragma unroll
                for (int nf = 0; nf < 4; ++nf) {
                    int col = n0 + wn * 64 + nf * 16 + l16;
                    out[(size_t)mr * 768 + col] = acc[mf][nf][r];
                }
            }
        }
    }
}

__global__ __launch_bounds__(512) void k_proj_shared(
    const bf16* __restrict__ Aact, const bf16* __restrict__ PT, float* __restrict__ out,
    const int* __restrict__ cnt, const int* __restrict__ offs, const float* __restrict__ wl) {
    proj_body<0>(Aact, PT, out, cnt, offs, wl);
}
__global__ __launch_bounds__(512) void k_proj_routed(
    const bf16* __restrict__ Aact, const bf16* __restrict__ PT, float* __restrict__ out,
    const int* __restrict__ cnt, const int* __restrict__ offs, const float* __restrict__ wl) {
    proj_body<1>(Aact, PT, out, cnt, offs, wl);
}

// ---------------- launch ----------------

extern "C" void kernel_launch(void* const* d_in, const int* in_sizes, int n_in,
                              void* d_out, int out_size, void* d_ws, size_t ws_size,
                              hipStream_t stream) {
    const float* x    = (const float*)d_in[0];
    const float* wfc  = (const float*)d_in[1];
    const float* wpr  = (const float*)d_in[2];
    const float* wefc = (const float*)d_in[3];
    const float* wepr = (const float*)d_in[4];
    const float* wg   = (const float*)d_in[5];
    const float* eb   = (const float*)d_in[6];
    float* out = (float*)d_out;

    char* p = (char*)d_ws;
    bf16* x_bf  = (bf16*)p; p += (size_t)8192 * 768 * 2;
    bf16* fcT_s = (bf16*)p; p += (size_t)6144 * 768 * 2;
    bf16* prT_s = (bf16*)p; p += (size_t)768 * 3072 * 2;
    bf16* fcT_e = (bf16*)p; p += (size_t)16 * 6144 * 768 * 2;   // dead after fc_routed
    bf16* prT_e = (bf16*)p; p += (size_t)16 * 768 * 3072 * 2;
    bf16* act_s = (bf16*)p; p += (size_t)8192 * 3072 * 2;
    bf16* act_r = (bf16*)p; p += (size_t)32768 * 3072 * 2;
    int* cnt    = (int*)p;  p += 64;
    int* offs   = (int*)p;  p += 64;
    int* tok    = (int*)p;  p += (size_t)16 * 8192 * 4;
    float* wl   = (float*)p; p += (size_t)16 * 8192 * 4;
    int* slotk  = (int*)p;  p += (size_t)8192 * 4 * 4;
    float* routed_out = (float*)fcT_e;  // aliases fcT_e (151 MB >= 100.7 MB)

    k_convert_x<<<dim3(6144), dim3(256), 0, stream>>>(x, x_bf, 8192 * 768, cnt);
    k_transpose64<<<dim3(96, 12, 1), dim3(256), 0, stream>>>(wfc, fcT_s, 768, 6144, 1);
    k_transpose64<<<dim3(12, 48, 1), dim3(256), 0, stream>>>(wpr, prT_s, 3072, 768, 0);
    k_transpose64<<<dim3(96, 12, 16), dim3(256), 0, stream>>>(wefc, fcT_e, 768, 6144, 1);
    k_transpose64<<<dim3(12, 48, 16), dim3(256), 0, stream>>>(wepr, prT_e, 3072, 768, 0);
    k_gate<<<dim3(512), dim3(256), 0, stream>>>(x, wg, eb, cnt, tok, wl, slotk);
    k_offsets<<<dim3(1), dim3(64), 0, stream>>>(cnt, offs);

    k_fc_shared<<<dim3(24, 32, 1), dim3(512), 0, stream>>>(x_bf, fcT_s, act_s, cnt, offs, tok);
    k_fc_routed<<<dim3(24, 32, 16), dim3(512), 0, stream>>>(x_bf, fcT_e, act_r, cnt, offs, tok);
    k_proj_shared<<<dim3(6, 32, 1), dim3(512), 0, stream>>>(act_s, prT_s, out, cnt, offs, wl);
    k_proj_routed<<<dim3(6, 32, 16), dim3(512), 0, stream>>>(act_r, prT_e, routed_out, cnt, offs, wl);
    k_combine<<<dim3(8192), dim3(192), 0, stream>>>(routed_out, slotk, offs, out);
}